// Round 4
// baseline (264.836 us; speedup 1.0000x reference)
//
#include <hip/hip_runtime.h>

#define LOG2E 1.4426950408889634f

constexpr int Dn = 128;
constexpr int Nn = 16384;
constexpr int Kn = 64;
constexpr int Bn = 16;

typedef __attribute__((ext_vector_type(16))) float f32x16;

// Prep: folds mu-normalize, exp(-log_sigma), factor -2, k-constant and log2e.
// Round-1 layout: wout[((k>>3)*64 + dh)*8 + (k&7)] — the 8-k slice of wave g
// at a given dh is 128 contiguous bytes (2x s_load_dwordx16).
__global__ __launch_bounds__(64) void gmm_prep(const float* __restrict__ mu,
                                               const float* __restrict__ log_sigma,
                                               const float* __restrict__ log_alpha,
                                               float4* __restrict__ wout,
                                               float* __restrict__ cout) {
    const int k = blockIdx.x;
    const int l = threadIdx.x;        // l == dh
    const int d0 = 2 * l;
    float m0 = mu[k * Dn + d0];
    float m1 = mu[k * Dn + d0 + 1];
    float s0 = log_sigma[k * Dn + d0];
    float s1 = log_sigma[k * Dn + d0 + 1];
    float nrm2 = m0 * m0 + m1 * m1;
    float lss = s0 + s1;
    #pragma unroll
    for (int off = 32; off > 0; off >>= 1) {
        nrm2 += __shfl_xor(nrm2, off);
        lss  += __shfl_xor(lss, off);
    }
    const float inv_nrm = 1.0f / fmaxf(sqrtf(nrm2), 1e-12f);
    const float mn0 = m0 * inv_nrm, mn1 = m1 * inv_nrm;
    const float si0 = expf(-s0), si1 = expf(-s1);
    float mt = mn0 * mn0 * si0 + mn1 * mn1 * si1;
    #pragma unroll
    for (int off = 32; off > 0; off >>= 1) mt += __shfl_xor(mt, off);
    wout[((k >> 3) * 64 + l) * 8 + (k & 7)] =
        make_float4(-si0 * LOG2E, 2.0f * mn0 * si0 * LOG2E,
                    -si1 * LOG2E, 2.0f * mn1 * si1 * LOG2E);
    if (l == 0) cout[k] = (log_alpha[k] - 0.5f * lss - mt) * LOG2E;
}

__device__ __forceinline__ float4 fmax4(float4 a, float4 b) {
    return make_float4(fmaxf(a.x, b.x), fmaxf(a.y, b.y),
                       fmaxf(a.z, b.z), fmaxf(a.w, b.w));
}
__device__ __forceinline__ float4 add4(float4 a, float4 b) {
    return make_float4(a.x + b.x, a.y + b.y, a.z + b.z, a.w + b.w);
}
__device__ __forceinline__ float4 sq4(float4 a) {
    return make_float4(a.x * a.x, a.y * a.y, a.z * a.z, a.w * a.w);
}

// Main v5 = round-1 structure (512 thr, 8 waves, 8k/wave, 4n/lane, 113us,
// spill-free codegen) + the one untested fix: DEFERRED W drain. Round 1/2's
// inner loop did s_load x2 + immediate lgkmcnt(0) -> every wave eats full
// scalar latency per 272 issue-cyc, stalls lockstep across waves = the 62%
// VALUBusy cap. SMEM returns out of order so counted lgkmcnt is illegal;
// instead: double-buffer W in SGPRs (4x f32x16), issue next-dh loads BEFORE
// the 136-instr compute block, drain AFTER it with the wait tied to the W
// regs via "+s" dataflow (rule: asm wait alone doesn't order reg-only
// consumers). x is likewise prefetched one dh ahead (8 extra arch VGPRs;
// cur+next x 16 + t 8 + addr ~6 = ~30 arch, acc 32 -> AGPR side, as round 1).
__global__ __launch_bounds__(512)
void gmm_main(const float* __restrict__ x,
              const float4* __restrict__ w,
              const float* __restrict__ cks,
              float* __restrict__ out) {
    __shared__ float sRed[8][256];     // 8 KB cross-wave softmax buffer

    const int tid = threadIdx.x;
    const int g = __builtin_amdgcn_readfirstlane(tid >> 6);  // wave id 0..7
    const int l = tid & 63;
    const int b = blockIdx.y;
    const int nloc = 4 * l;
    const size_t nbase = (size_t)blockIdx.x * 256 + nloc;

    // init acc with the per-k constant (folds the epilogue add)
    float acc[8][4];
    #pragma unroll
    for (int k = 0; k < 8; ++k) {
        const float c = cks[g * 8 + k];
        #pragma unroll
        for (int j = 0; j < 4; ++j) acc[k][j] = c;
    }

    const float* xp = x + (size_t)b * Dn * Nn + nbase;
    const char* wp = (const char*)w + (size_t)g * 8192;  // g-slice: 64dh*8k*16B

    // prologue: W(dh=0) and x(dh=0)
    f32x16 wA0, wA1, wB0, wB1;
    asm volatile("s_load_dwordx16 %0, %2, 0x0\n\t"
                 "s_load_dwordx16 %1, %2, 0x40"
                 : "=&s"(wA0), "=&s"(wA1) : "s"(wp));
    float4 xa0 = *(const float4*)(xp);
    float4 xb0 = *(const float4*)(xp + Nn);
    float4 xa1, xb1;
    asm volatile("s_waitcnt lgkmcnt(0)" : "+s"(wA0), "+s"(wA1));

// 4 k's from one f32x16 half WV (k = KB..KB+3); W quad per k:
// {wx0 (a, even d), wy0 (b, even d), wx1 (a, odd d), wy1 (b, odd d)}
#define GMM_K(WV, KK, A, TA, XA, TB, XB)                                  \
        {                                                                 \
            const float wx0 = WV[4 * KK + 0], wy0 = WV[4 * KK + 1];       \
            const float wx1 = WV[4 * KK + 2], wy1 = WV[4 * KK + 3];       \
            A[0] = fmaf(wx0, TA.x, A[0]); A[0] = fmaf(wy0, XA.x, A[0]);   \
            A[0] = fmaf(wx1, TB.x, A[0]); A[0] = fmaf(wy1, XB.x, A[0]);   \
            A[1] = fmaf(wx0, TA.y, A[1]); A[1] = fmaf(wy0, XA.y, A[1]);   \
            A[1] = fmaf(wx1, TB.y, A[1]); A[1] = fmaf(wy1, XB.y, A[1]);   \
            A[2] = fmaf(wx0, TA.z, A[2]); A[2] = fmaf(wy0, XA.z, A[2]);   \
            A[2] = fmaf(wx1, TB.z, A[2]); A[2] = fmaf(wy1, XB.z, A[2]);   \
            A[3] = fmaf(wx0, TA.w, A[3]); A[3] = fmaf(wy0, XA.w, A[3]);   \
            A[3] = fmaf(wx1, TB.w, A[3]); A[3] = fmaf(wy1, XB.w, A[3]);   \
        }
#define GMM_DH(W0, W1, TA, XA, TB, XB)                                    \
        GMM_K(W0, 0, acc[0], TA, XA, TB, XB)                              \
        GMM_K(W0, 1, acc[1], TA, XA, TB, XB)                              \
        GMM_K(W0, 2, acc[2], TA, XA, TB, XB)                              \
        GMM_K(W0, 3, acc[3], TA, XA, TB, XB)                              \
        GMM_K(W1, 0, acc[4], TA, XA, TB, XB)                              \
        GMM_K(W1, 1, acc[5], TA, XA, TB, XB)                              \
        GMM_K(W1, 2, acc[6], TA, XA, TB, XB)                              \
        GMM_K(W1, 3, acc[7], TA, XA, TB, XB)

    #pragma unroll 1
    for (int dh = 0; dh < Dn / 2; dh += 2) {
        // ---- stage A: compute dh (wA, xa0/xb0); prefetch dh+1 (wB, xa1/xb1)
        asm volatile("s_load_dwordx16 %0, %2, 0x80\n\t"
                     "s_load_dwordx16 %1, %2, 0xC0"
                     : "=&s"(wB0), "=&s"(wB1) : "s"(wp));
        {
            const float* xq = xp + 2 * Nn;          // dh+1 rows, always valid
            xa1 = *(const float4*)(xq);
            xb1 = *(const float4*)(xq + Nn);
        }
        {
            const float4 ta = sq4(xa0), tb = sq4(xb0);
            GMM_DH(wA0, wA1, ta, xa0, tb, xb0)
        }
        asm volatile("s_waitcnt lgkmcnt(0)" : "+s"(wB0), "+s"(wB1));

        // ---- stage B: compute dh+1 (wB, xa1/xb1); prefetch dh+2 (wA, xa0/xb0)
        // W read at dh=62 goes 128B past the g-slice: lands in the next slice
        // (or cbuf for g=7) — allocated, values unused after the loop.
        asm volatile("s_load_dwordx16 %0, %2, 0x100\n\t"
                     "s_load_dwordx16 %1, %2, 0x140"
                     : "=&s"(wA0), "=&s"(wA1) : "s"(wp));
        {
            const float* xq = (dh < Dn / 2 - 2) ? xp + 4 * Nn : xp;  // tail-safe
            xa0 = *(const float4*)(xq);
            xb0 = *(const float4*)(xq + Nn);
        }
        {
            const float4 ta = sq4(xa1), tb = sq4(xb1);
            GMM_DH(wB0, wB1, ta, xa1, tb, xb1)
        }
        asm volatile("s_waitcnt lgkmcnt(0)" : "+s"(wA0), "+s"(wA1));

        xp += 4 * Nn;
        wp += 256;
    }
#undef GMM_DH
#undef GMM_K

    // ---- softmax: cross-wave max over all 64 k ----
    float4 m = make_float4(acc[0][0], acc[0][1], acc[0][2], acc[0][3]);
    #pragma unroll
    for (int k = 1; k < 8; ++k)
        m = fmax4(m, make_float4(acc[k][0], acc[k][1], acc[k][2], acc[k][3]));
    *(float4*)&sRed[g][nloc] = m;
    __syncthreads();
    #pragma unroll
    for (int gg = 0; gg < 8; ++gg)
        m = fmax4(m, *(const float4*)&sRed[gg][nloc]);
    __syncthreads();   // before reusing sRed for sums

    // ---- exp2 + cross-wave sum ----
    float4 s = make_float4(0.f, 0.f, 0.f, 0.f);
    #pragma unroll
    for (int k = 0; k < 8; ++k) {
        acc[k][0] = __builtin_amdgcn_exp2f(acc[k][0] - m.x); s.x += acc[k][0];
        acc[k][1] = __builtin_amdgcn_exp2f(acc[k][1] - m.y); s.y += acc[k][1];
        acc[k][2] = __builtin_amdgcn_exp2f(acc[k][2] - m.z); s.z += acc[k][2];
        acc[k][3] = __builtin_amdgcn_exp2f(acc[k][3] - m.w); s.w += acc[k][3];
    }
    *(float4*)&sRed[g][nloc] = s;
    __syncthreads();
    s = make_float4(0.f, 0.f, 0.f, 0.f);
    #pragma unroll
    for (int gg = 0; gg < 8; ++gg)
        s = add4(s, *(const float4*)&sRed[gg][nloc]);
    const float4 r = make_float4(1.0f / s.x, 1.0f / s.y, 1.0f / s.z, 1.0f / s.w);

    // ---- store: out[b][k][n], one float4 per k, coalesced ----
    float* op = out + (size_t)(b * Kn + g * 8) * Nn + nbase;
    #pragma unroll
    for (int k = 0; k < 8; ++k) {
        *(float4*)op = make_float4(acc[k][0] * r.x, acc[k][1] * r.y,
                                   acc[k][2] * r.z, acc[k][3] * r.w);
        op += Nn;
    }
}

extern "C" void kernel_launch(void* const* d_in, const int* in_sizes, int n_in,
                              void* d_out, int out_size, void* d_ws, size_t ws_size,
                              hipStream_t stream) {
    const float* x  = (const float*)d_in[0];
    const float* mu = (const float*)d_in[1];
    const float* ls = (const float*)d_in[2];
    const float* la = (const float*)d_in[3];
    float* out = (float*)d_out;

    float4* wbuf = (float4*)d_ws;
    float*  cbuf = (float*)((char*)d_ws + (size_t)Kn * (Dn / 2) * sizeof(float4));

    gmm_prep<<<dim3(Kn), dim3(64), 0, stream>>>(mu, ls, la, wbuf, cbuf);
    gmm_main<<<dim3(Nn / 256, Bn), dim3(512), 0, stream>>>(x, wbuf, cbuf, out);
}